// Round 1
// baseline (133.869 us; speedup 1.0000x reference)
//
#include <hip/hip_runtime.h>

// Pink-noise 6-pole IIR, parallelized as an affine (linear-recurrence) scan.
// white: [B, 65536] f32 -> pink: [B, 65536] f32.
// One block per channel; 512 threads; each thread owns a contiguous chunk of
// 128 time steps. Pass 1 computes each chunk's end-state from zero init; a
// block-wide affine scan (shuffle intra-wave + LDS across 8 waves) yields the
// true incoming state per chunk; pass 2 recomputes the chunk with the correct
// init and writes outputs.

constexpr int kL = 65536;
constexpr int kThreads = 512;
constexpr int kChunk = kL / kThreads;  // 128 = 2^7
constexpr int kVec = kChunk / 4;       // 32 float4 loads per pass

__global__ __launch_bounds__(kThreads) void pink_kernel(
    const float* __restrict__ white, float* __restrict__ pink)
{
    constexpr float A0 = 0.99886f, A1 = 0.99332f, A2 = 0.969f,
                    A3 = 0.8665f,  A4 = 0.55f,    A5 = -0.7616f;
    constexpr float C0 = 0.0555179f, C1 = 0.0750759f, C2 = 0.153852f,
                    C3 = 0.3104856f, C4 = 0.5329522f, C5 = -0.016898f;
    constexpr float B6G = 0.115926f, DIRECT = 0.5362f, OUTG = 0.11f;

    const int ch   = blockIdx.x;
    const int tid  = threadIdx.x;
    const int lane = tid & 63;
    const int wave = tid >> 6;

    const float* __restrict__ wrow = white + (size_t)ch * kL;
    float* __restrict__ prow       = pink  + (size_t)ch * kL;
    const int t0 = tid * kChunk;

    const float4* __restrict__ wv = (const float4*)(wrow + t0);

    // ---- Pass 1: local scan with zero init -> end state e[6] ----
    float e0 = 0.f, e1 = 0.f, e2 = 0.f, e3 = 0.f, e4 = 0.f, e5 = 0.f;
    {
        auto step1 = [&](float w) {
            e0 = fmaf(A0, e0, w * C0);
            e1 = fmaf(A1, e1, w * C1);
            e2 = fmaf(A2, e2, w * C2);
            e3 = fmaf(A3, e3, w * C3);
            e4 = fmaf(A4, e4, w * C4);
            e5 = fmaf(A5, e5, w * C5);
        };
        #pragma unroll 4
        for (int i = 0; i < kVec; ++i) {
            float4 w4 = wv[i];
            step1(w4.x); step1(w4.y); step1(w4.z); step1(w4.w);
        }
    }

    // multiplier m = a^kChunk via 7 squarings (kChunk = 128 = 2^7)
    float m0 = A0, m1 = A1, m2 = A2, m3 = A3, m4 = A4, m5 = A5;
    #pragma unroll
    for (int i = 0; i < 7; ++i) {
        m0 *= m0; m1 *= m1; m2 *= m2; m3 *= m3; m4 *= m4; m5 *= m5;
    }

    // ---- Intra-wave inclusive affine scan (Hillis-Steele, 64 lanes) ----
    // Pair (m, e) represents f(x) = m*x + e (composition of this thread's
    // span of chunks). Combine self∘from: e' = m_self*e_from + e_self,
    // m' = m_self*m_from.
    #pragma unroll
    for (int off = 1; off < 64; off <<= 1) {
        float fm0 = __shfl_up(m0, off), fe0 = __shfl_up(e0, off);
        float fm1 = __shfl_up(m1, off), fe1 = __shfl_up(e1, off);
        float fm2 = __shfl_up(m2, off), fe2 = __shfl_up(e2, off);
        float fm3 = __shfl_up(m3, off), fe3 = __shfl_up(e3, off);
        float fm4 = __shfl_up(m4, off), fe4 = __shfl_up(e4, off);
        float fm5 = __shfl_up(m5, off), fe5 = __shfl_up(e5, off);
        if (lane >= off) {
            e0 = fmaf(m0, fe0, e0); m0 *= fm0;
            e1 = fmaf(m1, fe1, e1); m1 *= fm1;
            e2 = fmaf(m2, fe2, e2); m2 *= fm2;
            e3 = fmaf(m3, fe3, e3); m3 *= fm3;
            e4 = fmaf(m4, fe4, e4); m4 *= fm4;
            e5 = fmaf(m5, fe5, e5); m5 *= fm5;
        }
    }

    // ---- Cross-wave: wave totals via LDS ----
    __shared__ float sm[8][6];
    __shared__ float se[8][6];
    if (lane == 63) {
        sm[wave][0] = m0; sm[wave][1] = m1; sm[wave][2] = m2;
        sm[wave][3] = m3; sm[wave][4] = m4; sm[wave][5] = m5;
        se[wave][0] = e0; se[wave][1] = e1; se[wave][2] = e2;
        se[wave][3] = e3; se[wave][4] = e4; se[wave][5] = e5;
    }
    __syncthreads();

    // State after all waves before this one (global init is 0, so the state
    // equals the composed offset term).
    float E0 = 0.f, E1 = 0.f, E2 = 0.f, E3 = 0.f, E4 = 0.f, E5 = 0.f;
    for (int w2 = 0; w2 < wave; ++w2) {
        E0 = fmaf(sm[w2][0], E0, se[w2][0]);
        E1 = fmaf(sm[w2][1], E1, se[w2][1]);
        E2 = fmaf(sm[w2][2], E2, se[w2][2]);
        E3 = fmaf(sm[w2][3], E3, se[w2][3]);
        E4 = fmaf(sm[w2][4], E4, se[w2][4]);
        E5 = fmaf(sm[w2][5], E5, se[w2][5]);
    }

    // Exclusive intra-wave scan = inclusive shifted up by one lane.
    float xm0 = __shfl_up(m0, 1), xe0 = __shfl_up(e0, 1);
    float xm1 = __shfl_up(m1, 1), xe1 = __shfl_up(e1, 1);
    float xm2 = __shfl_up(m2, 1), xe2 = __shfl_up(e2, 1);
    float xm3 = __shfl_up(m3, 1), xe3 = __shfl_up(e3, 1);
    float xm4 = __shfl_up(m4, 1), xe4 = __shfl_up(e4, 1);
    float xm5 = __shfl_up(m5, 1), xe5 = __shfl_up(e5, 1);
    if (lane == 0) {
        xm0 = 1.f; xe0 = 0.f; xm1 = 1.f; xe1 = 0.f; xm2 = 1.f; xe2 = 0.f;
        xm3 = 1.f; xe3 = 0.f; xm4 = 1.f; xe4 = 0.f; xm5 = 1.f; xe5 = 0.f;
    }

    // Incoming pole state for this thread's chunk.
    float b0 = fmaf(xm0, E0, xe0);
    float b1 = fmaf(xm1, E1, xe1);
    float b2 = fmaf(xm2, E2, xe2);
    float b3 = fmaf(xm3, E3, xe3);
    float b4 = fmaf(xm4, E4, xe4);
    float b5 = fmaf(xm5, E5, xe5);

    // b6 state = scaled previous white sample (0 at t=0).
    float b6 = (t0 == 0) ? 0.f : B6G * wrow[t0 - 1];

    // ---- Pass 2: recompute chunk with correct init, write outputs ----
    float4* __restrict__ pv = (float4*)(prow + t0);
    auto step2 = [&](float w) -> float {
        b0 = fmaf(A0, b0, w * C0);
        b1 = fmaf(A1, b1, w * C1);
        b2 = fmaf(A2, b2, w * C2);
        b3 = fmaf(A3, b3, w * C3);
        b4 = fmaf(A4, b4, w * C4);
        b5 = fmaf(A5, b5, w * C5);
        float s = ((b0 + b1) + (b2 + b3)) + ((b4 + b5) + b6);
        float pk = (s + DIRECT * w) * OUTG;
        b6 = B6G * w;
        return pk;
    };
    #pragma unroll 4
    for (int i = 0; i < kVec; ++i) {
        float4 w4 = wv[i];
        float4 o;
        o.x = step2(w4.x);
        o.y = step2(w4.y);
        o.z = step2(w4.z);
        o.w = step2(w4.w);
        pv[i] = o;
    }
}

extern "C" void kernel_launch(void* const* d_in, const int* in_sizes, int n_in,
                              void* d_out, int out_size, void* d_ws, size_t ws_size,
                              hipStream_t stream) {
    const float* white = (const float*)d_in[0];
    float* pink = (float*)d_out;
    const int B = in_sizes[0] / kL;  // 256 channels for the reference shape
    hipLaunchKernelGGL(pink_kernel, dim3(B), dim3(kThreads), 0, stream,
                       white, pink);
}